// Round 1
// baseline (3419.823 us; speedup 1.0000x reference)
//
#include <hip/hip_runtime.h>
#include <math.h>

// Problem constants (B, D_IN, H, NZ, NC)
#define BN    32768
#define DIN   768
#define HN    2048
#define NZ    128
#define NCN   1024

// Outputs (flat, f32): [0]=loss, [1..BN]=batch_assignments, then soft_counts,
// new_raw, new_cluster, new_total_soft (each NCN). Total 1+BN+4*NCN = 36865.

// ---------------- K0: init (u=1, histograms=0) ----------------
__global__ __launch_bounds__(1024) void k0_init(float* u, int* hraw, int* hclu){
  const int k = threadIdx.x;
  u[k] = 1.0f;
  hraw[k] = 0;
  hclu[k] = 0;
}

// ---------------- K1: fused backbone fv = relu(X@W1+b1)@W2 + b2 ----------------
// Block: 256 threads, 64 rows. LDS: BufB [64][68] (W1 tile, then A1 tile),
// BufA (Xs [64][68] in phase A, W2s [64][128] in phase B). 50 KB total.
__global__ __launch_bounds__(256) void k1_backbone(
    const float* __restrict__ X, const float* __restrict__ W1,
    const float* __restrict__ b1, const float* __restrict__ W2,
    const float* __restrict__ b2, float* __restrict__ fv)
{
  __shared__ __align__(16) float smem[12544];
  float* BufB = smem;          // [64][68]: W1 tile, then relu(A1) tile
  float* BufA = smem + 4352;   // Xs [64][68] (phase A) / W2s [64][128] (phase B)

  const int t  = threadIdx.x;
  const int tx = t & 15, ty = t >> 4;
  const int row0 = blockIdx.x * 64;

  float fvacc[4][8];
  #pragma unroll
  for (int i=0;i<4;++i)
    #pragma unroll
    for (int j=0;j<8;++j) fvacc[i][j] = 0.f;

  for (int hc = 0; hc < HN; hc += 64) {
    float a1[4][4];
    #pragma unroll
    for (int i=0;i<4;++i)
      #pragma unroll
      for (int j=0;j<4;++j) a1[i][j] = 0.f;

    for (int kc = 0; kc < DIN; kc += 64) {
      #pragma unroll
      for (int m=0;m<4;++m){
        int idx4 = t + 256*m;
        int r  = idx4 >> 4;
        int c4 = (idx4 & 15) << 2;
        *(float4*)&BufA[r*68 + c4] = *(const float4*)&X [(size_t)(row0 + r)*DIN + kc + c4];
        *(float4*)&BufB[r*68 + c4] = *(const float4*)&W1[(size_t)(kc  + r)*HN  + hc + c4];
      }
      __syncthreads();
      #pragma unroll
      for (int kk=0; kk<64; kk+=4){
        float4 xa[4], wb[4];
        #pragma unroll
        for (int i=0;i<4;++i)  xa[i]  = *(const float4*)&BufA[(4*ty+i)*68 + kk];
        #pragma unroll
        for (int kq=0;kq<4;++kq) wb[kq] = *(const float4*)&BufB[(kk+kq)*68 + 4*tx];
        #pragma unroll
        for (int kq=0;kq<4;++kq){
          #pragma unroll
          for (int i=0;i<4;++i){
            float xv = (kq==0)?xa[i].x:(kq==1)?xa[i].y:(kq==2)?xa[i].z:xa[i].w;
            a1[i][0] += xv*wb[kq].x;
            a1[i][1] += xv*wb[kq].y;
            a1[i][2] += xv*wb[kq].z;
            a1[i][3] += xv*wb[kq].w;
          }
        }
      }
      __syncthreads();
    }
    // bias + relu, store A1 tile into BufB
    #pragma unroll
    for (int j=0;j<4;++j){
      float bj = b1[hc + 4*tx + j];
      #pragma unroll
      for (int i=0;i<4;++i){
        float v = a1[i][j] + bj;
        a1[i][j] = v > 0.f ? v : 0.f;
      }
    }
    #pragma unroll
    for (int i=0;i<4;++i){
      float4 v; v.x=a1[i][0]; v.y=a1[i][1]; v.z=a1[i][2]; v.w=a1[i][3];
      *(float4*)&BufB[(4*ty+i)*68 + 4*tx] = v;
    }
    // stage W2 chunk [64][128] into BufA
    #pragma unroll
    for (int m=0;m<8;++m){
      int idx4 = t + 256*m;
      int r  = idx4 >> 5;
      int c4 = (idx4 & 31) << 2;
      *(float4*)&BufA[r*128 + c4] = *(const float4*)&W2[(size_t)(hc + r)*NZ + c4];
    }
    __syncthreads();
    #pragma unroll
    for (int kk=0; kk<64; kk+=4){
      float4 aa[4], wc0[4], wc1[4];
      #pragma unroll
      for (int i=0;i<4;++i) aa[i] = *(const float4*)&BufB[(4*ty+i)*68 + kk];
      #pragma unroll
      for (int kq=0;kq<4;++kq){
        wc0[kq] = *(const float4*)&BufA[(kk+kq)*128 + 8*tx];
        wc1[kq] = *(const float4*)&BufA[(kk+kq)*128 + 8*tx + 4];
      }
      #pragma unroll
      for (int kq=0;kq<4;++kq){
        #pragma unroll
        for (int i=0;i<4;++i){
          float av = (kq==0)?aa[i].x:(kq==1)?aa[i].y:(kq==2)?aa[i].z:aa[i].w;
          fvacc[i][0]+=av*wc0[kq].x; fvacc[i][1]+=av*wc0[kq].y;
          fvacc[i][2]+=av*wc0[kq].z; fvacc[i][3]+=av*wc0[kq].w;
          fvacc[i][4]+=av*wc1[kq].x; fvacc[i][5]+=av*wc1[kq].y;
          fvacc[i][6]+=av*wc1[kq].z; fvacc[i][7]+=av*wc1[kq].w;
        }
      }
    }
    __syncthreads();
  }
  #pragma unroll
  for (int i=0;i<4;++i){
    int row = row0 + 4*ty + i;
    float4 v0, v1;
    v0.x = fvacc[i][0] + b2[8*tx+0];
    v0.y = fvacc[i][1] + b2[8*tx+1];
    v0.z = fvacc[i][2] + b2[8*tx+2];
    v0.w = fvacc[i][3] + b2[8*tx+3];
    v1.x = fvacc[i][4] + b2[8*tx+4];
    v1.y = fvacc[i][5] + b2[8*tx+5];
    v1.z = fvacc[i][6] + b2[8*tx+6];
    v1.w = fvacc[i][7] + b2[8*tx+7];
    *(float4*)&fv[(size_t)row*NZ + 8*tx]     = v0;
    *(float4*)&fv[(size_t)row*NZ + 8*tx + 4] = v1;
  }
}

// ---------------- K2: dist -> Q0 = exp(-2*dist), row-major [BN][NCN] ----------------
// Block: 256 threads, 32 rows; centroid chunks of 64. XOR-swizzled LDS tiles
// (rule #21: swizzle applied on write AND read with the same involution).
__global__ __launch_bounds__(256) void k2_dist(
    const float* __restrict__ fv, const float* __restrict__ cent,
    float* __restrict__ Q0)
{
  __shared__ __align__(16) float fvs[32*128];
  __shared__ __align__(16) float cs[64*128];
  __shared__ float fvn[32];
  __shared__ float cn[64];
  const int t = threadIdx.x;
  const int tx = t & 15, ty = t >> 4;
  const int row0 = blockIdx.x * 32;

  #pragma unroll
  for (int m=0;m<4;++m){
    int idx4 = t + 256*m;
    int r  = idx4 >> 5;
    int c4 = (idx4 & 31) << 2;
    *(float4*)&fvs[r*128 + (c4 ^ ((((r>>1)&7))<<2))] =
        *(const float4*)&fv[(size_t)(row0 + r)*NZ + c4];
  }
  __syncthreads();
  if (t < 32){
    int xw = ((t>>1)&7)<<2;
    float s = 0.f;
    for (int z=0;z<NZ;z+=4){
      const float4 v = *(const float4*)&fvs[t*128 + (z ^ xw)];
      s += v.x*v.x; s += v.y*v.y; s += v.z*v.z; s += v.w*v.w;
    }
    fvn[t] = s;
  }

  for (int cc = 0; cc < NCN; cc += 64){
    #pragma unroll
    for (int m=0;m<8;++m){
      int idx4 = t + 256*m;
      int r  = idx4 >> 5;
      int c4 = (idx4 & 31) << 2;
      *(float4*)&cs[r*128 + (c4 ^ ((((r>>3)&7))<<2))] =
          *(const float4*)&cent[(size_t)(cc + r)*NZ + c4];
    }
    __syncthreads();
    if (t < 64){
      int xw = ((t>>3)&7)<<2;
      float s = 0.f;
      for (int z=0;z<NZ;z+=4){
        const float4 v = *(const float4*)&cs[t*128 + (z ^ xw)];
        s += v.x*v.x; s += v.y*v.y; s += v.z*v.z; s += v.w*v.w;
      }
      cn[t] = s;
    }
    __syncthreads();

    float acc[2][4];
    #pragma unroll
    for (int i=0;i<2;++i)
      #pragma unroll
      for (int j=0;j<4;++j) acc[i][j]=0.f;

    const int xwf = (ty&7)<<2;
    const int xwc = ((tx>>1)&7)<<2;
    #pragma unroll 4
    for (int kk=0; kk<NZ; kk+=4){
      float4 fq0 = *(const float4*)&fvs[(2*ty+0)*128 + (kk ^ xwf)];
      float4 fq1 = *(const float4*)&fvs[(2*ty+1)*128 + (kk ^ xwf)];
      float4 cb[4];
      #pragma unroll
      for (int j=0;j<4;++j)
        cb[j] = *(const float4*)&cs[(4*tx+j)*128 + (kk ^ xwc)];
      #pragma unroll
      for (int j=0;j<4;++j){
        acc[0][j] += fq0.x*cb[j].x; acc[0][j] += fq0.y*cb[j].y;
        acc[0][j] += fq0.z*cb[j].z; acc[0][j] += fq0.w*cb[j].w;
        acc[1][j] += fq1.x*cb[j].x; acc[1][j] += fq1.y*cb[j].y;
        acc[1][j] += fq1.z*cb[j].z; acc[1][j] += fq1.w*cb[j].w;
      }
    }
    #pragma unroll
    for (int i=0;i<2;++i){
      int row = row0 + 2*ty + i;
      float fnv = fvn[2*ty+i];
      float o[4];
      #pragma unroll
      for (int j=0;j<4;++j){
        float sq = fnv + cn[4*tx+j] - 2.0f*acc[i][j];
        sq = sq > 1e-12f ? sq : 1e-12f;
        float d = sqrtf(sq);
        o[j] = expf(-2.0f*d);
      }
      float4 ov; ov.x=o[0]; ov.y=o[1]; ov.z=o[2]; ov.w=o[3];
      *(float4*)&Q0[(size_t)row*NCN + cc + 4*tx] = ov;
    }
    __syncthreads();
  }
}

// ---------------- K3: one fused sinkhorn pass ----------------
// For each column b: T_b = sum_k u_k*q, v = alpha/T_b, S_k += q*v.
// Wave-per-row, per-wave LDS S accumulator, per-block partials (deterministic).
__global__ __launch_bounds__(256) void k3_pass(
    const float* __restrict__ Q0, const float* __restrict__ u,
    float* __restrict__ S_part, float alpha)
{
  __shared__ __align__(16) float ul[NCN];
  __shared__ __align__(16) float Sw[4][NCN];
  const int t = threadIdx.x;
  const int w = t >> 6, l = t & 63;
  #pragma unroll
  for (int m=0;m<4;++m) ul[t + 256*m] = u[t + 256*m];
  #pragma unroll
  for (int m=0;m<16;++m) (&Sw[0][0])[t + 256*m] = 0.f;
  __syncthreads();

  const float4* ul4 = (const float4*)ul;
  float4* Sw4 = (float4*)&Sw[w][0];
  const int gw = blockIdx.x*4 + w;          // 0..2047
  const size_t b0 = (size_t)gw * 16;
  for (int rr=0; rr<16; ++rr){
    const float4* qrow = (const float4*)(Q0 + (b0 + rr)*NCN);
    float4 q4[4];
    float part = 0.f;
    #pragma unroll
    for (int j=0;j<4;++j){
      q4[j] = qrow[l + 64*j];
      float4 uu = ul4[l + 64*j];
      part += q4[j].x*uu.x; part += q4[j].y*uu.y;
      part += q4[j].z*uu.z; part += q4[j].w*uu.w;
    }
    #pragma unroll
    for (int off=32; off; off>>=1) part += __shfl_xor(part, off, 64);
    const float v = alpha / part;
    #pragma unroll
    for (int j=0;j<4;++j){
      float4 s = Sw4[l + 64*j];
      s.x += q4[j].x*v; s.y += q4[j].y*v; s.z += q4[j].z*v; s.w += q4[j].w*v;
      Sw4[l + 64*j] = s;
    }
  }
  __syncthreads();
  #pragma unroll
  for (int m=0;m<4;++m){
    int k = t + 256*m;
    S_part[(size_t)blockIdx.x*NCN + k] = ((Sw[0][k]+Sw[1][k])+(Sw[2][k]+Sw[3][k]));
  }
}

// ---------------- K4: u = r / colsum(S_part) ----------------
__global__ __launch_bounds__(1024) void k4_unew(
    const float* __restrict__ S_part, float* __restrict__ u)
{
  const int k = threadIdx.x;
  float s0=0.f,s1=0.f,s2=0.f,s3=0.f;
  for (int blk=0; blk<512; blk+=4){
    s0 += S_part[(size_t)(blk+0)*NCN + k];
    s1 += S_part[(size_t)(blk+1)*NCN + k];
    s2 += S_part[(size_t)(blk+2)*NCN + k];
    s3 += S_part[(size_t)(blk+3)*NCN + k];
  }
  u[k] = (1.0f/1024.0f) / ((s0+s1)+(s2+s3));
}

// ---------------- K5: final pass ----------------
__device__ __forceinline__ float comp4(const float4 v, int c){
  return (c==0)?v.x:(c==1)?v.y:(c==2)?v.z:v.w;
}

__global__ __launch_bounds__(256) void k5_final(
    const float* __restrict__ Q0, const float* __restrict__ u,
    float* __restrict__ softc_part, float* __restrict__ loss_part,
    int* __restrict__ hist_raw, int* __restrict__ hist_clu,
    float* __restrict__ out_ba)
{
  __shared__ __align__(16) float ul[NCN];
  __shared__ __align__(16) float Sw[4][NCN];
  __shared__ float lossw[4];
  const int t = threadIdx.x;
  const int w = t >> 6, l = t & 63;
  #pragma unroll
  for (int m=0;m<4;++m) ul[t + 256*m] = u[t + 256*m];
  #pragma unroll
  for (int m=0;m<16;++m) (&Sw[0][0])[t + 256*m] = 0.f;
  __syncthreads();

  const float4* ul4 = (const float4*)ul;
  float4* Sw4 = (float4*)&Sw[w][0];
  const int gw = blockIdx.x*4 + w;          // 0..1023
  const size_t b0 = (size_t)gw * 32;
  float lacc = 0.f;
  for (int rr=0; rr<32; ++rr){
    const size_t b = b0 + rr;
    const float4* qrow = (const float4*)(Q0 + b*NCN);
    float4 q4[4], wv4[4];
    float part = 0.f;
    #pragma unroll
    for (int j=0;j<4;++j){
      q4[j] = qrow[l + 64*j];
      float4 uu = ul4[l + 64*j];
      wv4[j].x = uu.x*q4[j].x; wv4[j].y = uu.y*q4[j].y;
      wv4[j].z = uu.z*q4[j].z; wv4[j].w = uu.w*q4[j].w;
      part += wv4[j].x; part += wv4[j].y; part += wv4[j].z; part += wv4[j].w;
    }
    #pragma unroll
    for (int off=32; off; off>>=1) part += __shfl_xor(part, off, 64);
    const float inv = 1.0f / part;

    // local scan in ascending-k order (k = 4l + 256j + c), strict compares ->
    // numpy first-index tie-breaking.
    float smin = wv4[0].x * inv; int kmin = 4*l; float qat = q4[0].x;
    float qmax = q4[0].x;        int kmax = 4*l;
    #pragma unroll
    for (int j=0;j<4;++j){
      #pragma unroll
      for (int c=0;c<4;++c){
        if (j==0 && c==0) continue;
        float qv = comp4(q4[j], c);
        float sv = comp4(wv4[j], c) * inv;
        int k = 4*l + 256*j + c;
        if (sv < smin){ smin = sv; kmin = k; qat = qv; }
        if (qv > qmax){ qmax = qv; kmax = k; }
      }
    }
    #pragma unroll
    for (int off=32; off; off>>=1){
      float s2 = __shfl_xor(smin, off, 64);
      int   k2 = __shfl_xor(kmin, off, 64);
      float q2 = __shfl_xor(qat,  off, 64);
      if (s2 < smin || (s2 == smin && k2 < kmin)){ smin=s2; kmin=k2; qat=q2; }
      float m2 = __shfl_xor(qmax, off, 64);
      int   i2 = __shfl_xor(kmax, off, 64);
      if (m2 > qmax || (m2 == qmax && i2 < kmax)){ qmax=m2; kmax=i2; }
    }
    #pragma unroll
    for (int j=0;j<4;++j){
      float4 s = Sw4[l + 64*j];
      s.x += wv4[j].x*inv; s.y += wv4[j].y*inv;
      s.z += wv4[j].z*inv; s.w += wv4[j].w*inv;
      Sw4[l + 64*j] = s;
    }
    if (l == 0){
      out_ba[b] = (float)kmin;                  // batch_assignments (argmin soft)
      atomicAdd(&hist_clu[kmin], 1);            // cluster_counts hist
      atomicAdd(&hist_raw[kmax], 1);            // raw_counts hist (argmin dist)
      lacc += -0.5f * logf(qat);                // dist at batch assignment
    }
  }
  if (l == 0) lossw[w] = lacc;
  __syncthreads();
  #pragma unroll
  for (int m=0;m<4;++m){
    int k = t + 256*m;
    softc_part[(size_t)blockIdx.x*NCN + k] = ((Sw[0][k]+Sw[1][k])+(Sw[2][k]+Sw[3][k]));
  }
  if (t == 0) loss_part[blockIdx.x] = ((lossw[0]+lossw[1])+(lossw[2]+lossw[3]));
}

// ---------------- K6: deterministic combine + output write ----------------
__global__ __launch_bounds__(1024) void k6_fin(
    const float* __restrict__ softc_part, const float* __restrict__ loss_part,
    const int* __restrict__ hist_raw, const int* __restrict__ hist_clu,
    const int* __restrict__ raw_in, const int* __restrict__ clu_in,
    const float* __restrict__ tsoft_in, float* __restrict__ out)
{
  const int k = threadIdx.x;
  float s0=0.f,s1=0.f,s2=0.f,s3=0.f;
  for (int blk=0; blk<256; blk+=4){
    s0 += softc_part[(size_t)(blk+0)*NCN + k];
    s1 += softc_part[(size_t)(blk+1)*NCN + k];
    s2 += softc_part[(size_t)(blk+2)*NCN + k];
    s3 += softc_part[(size_t)(blk+3)*NCN + k];
  }
  const float s = ((s0+s1)+(s2+s3));
  out[1 + BN + k]           = s;                                   // soft_counts
  out[1 + BN + NCN + k]     = (float)(raw_in[k] + hist_raw[k]);    // new_raw
  out[1 + BN + 2*NCN + k]   = (float)(clu_in[k] + hist_clu[k]);    // new_cluster
  out[1 + BN + 3*NCN + k]   = tsoft_in[k] + s;                     // new_total_soft
  if (k == 0){
    float ls = 0.f;
    for (int i=0;i<256;++i) ls += loss_part[i];
    out[0] = ls / 32768.0f;                                        // loss
  }
}

extern "C" void kernel_launch(void* const* d_in, const int* in_sizes, int n_in,
                              void* d_out, int out_size, void* d_ws, size_t ws_size,
                              hipStream_t stream) {
  (void)in_sizes; (void)n_in; (void)out_size; (void)ws_size;
  const float* x      = (const float*)d_in[0];
  const float* W1     = (const float*)d_in[1];
  const float* b1     = (const float*)d_in[2];
  const float* W2     = (const float*)d_in[3];
  const float* b2     = (const float*)d_in[4];
  const float* cent   = (const float*)d_in[5];
  const int*   clu_in = (const int*)d_in[6];
  const int*   raw_in = (const int*)d_in[7];
  const float* tsoft  = (const float*)d_in[8];
  float* out = (float*)d_out;

  // ws layout (floats): fv[BN*NZ], Q0[BN*NCN], u[NCN], S_part[512*NCN],
  // softc_part[256*NCN], loss_part[256], hist_raw[NCN](int), hist_clu[NCN](int)
  float* ws        = (float*)d_ws;
  float* fv        = ws;                      // 4194304
  float* Q0        = ws + 4194304;            // 33554432
  float* u         = Q0 + 33554432;           // 1024
  float* S_part    = u + 1024;                // 524288
  float* softc_par = S_part + 512*1024;       // 262144
  float* loss_par  = softc_par + 256*1024;    // 256
  int*   hist_raw  = (int*)(loss_par + 256);  // 1024
  int*   hist_clu  = hist_raw + 1024;         // 1024

  k0_init<<<1, 1024, 0, stream>>>(u, hist_raw, hist_clu);
  k1_backbone<<<512, 256, 0, stream>>>(x, W1, b1, W2, b2, fv);
  k2_dist<<<1024, 256, 0, stream>>>(fv, cent, Q0);
  for (int it = 0; it < 15; ++it){
    const float alpha = (it == 0) ? 1.0f : (1.0f/32768.0f);
    k3_pass<<<512, 256, 0, stream>>>(Q0, u, S_part, alpha);
    k4_unew<<<1, 1024, 0, stream>>>(S_part, u);
  }
  k5_final<<<256, 256, 0, stream>>>(Q0, u, softc_par, loss_par,
                                    hist_raw, hist_clu, out + 1);
  k6_fin<<<1, 1024, 0, stream>>>(softc_par, loss_par, hist_raw, hist_clu,
                                 raw_in, clu_in, tsoft, out);
}

// Round 2
// 1451.013 us; speedup vs baseline: 2.3569x; 2.3569x over previous
//
#include <hip/hip_runtime.h>
#include <math.h>

// Problem constants (B, D_IN, H, NZ, NC)
#define BN    32768
#define DIN   768
#define HN    2048
#define NZ    128
#define NCN   1024

typedef __attribute__((ext_vector_type(8))) short s16x8;
typedef __attribute__((ext_vector_type(4))) float f32x4;
typedef unsigned short u16;

#define MFMA16(a,b,c) __builtin_amdgcn_mfma_f32_16x16x32_bf16(a,b,c,0,0,0)

__device__ __forceinline__ u16 bf16_rne(float x){
  unsigned u = __float_as_uint(x);
  unsigned r = (u + 0x7FFFu + ((u >> 16) & 1u)) >> 16;
  return (u16)r;
}
__device__ __forceinline__ float bf16_tof(u16 h){
  return __uint_as_float(((unsigned)h) << 16);
}
__device__ __forceinline__ void split3(float x, u16& h, u16& m, u16& l){
  h = bf16_rne(x);
  float r1 = x - bf16_tof(h);
  m = bf16_rne(r1);
  float r2 = r1 - bf16_tof(m);
  l = bf16_rne(r2);
}

__device__ __forceinline__ void gload16(const void* gsrc, void* lds){
  __builtin_amdgcn_global_load_lds(
      (const __attribute__((address_space(1))) unsigned int*)gsrc,
      (__attribute__((address_space(3))) unsigned int*)lds, 16, 0, 0);
}

// ---------------- K0: init (u=1, histograms=0) ----------------
__global__ __launch_bounds__(1024) void k0_init(float* u, int* hraw, int* hclu){
  const int k = threadIdx.x;
  u[k] = 1.0f;
  hraw[k] = 0;
  hclu[k] = 0;
}

// ---------------- Convert: transpose + 3-way bf16 split ----------------
// in [R][C] f32 -> oh/om/ol [C][R] bf16(u16)
__global__ __launch_bounds__(256) void c_tsplit(
    const float* __restrict__ in, int R, int C,
    u16* __restrict__ oh, u16* __restrict__ om, u16* __restrict__ ol)
{
  __shared__ float L[64][65];
  const int t = threadIdx.x;
  const int bi = blockIdx.x, bj = blockIdx.y;
  #pragma unroll
  for (int m=0;m<4;++m){
    int flat = t + 256*m;
    int r = flat >> 4, c4 = (flat & 15) << 2;
    const float4 v = *(const float4*)&in[(size_t)(bi*64 + r)*C + bj*64 + c4];
    L[r][c4+0] = v.x; L[r][c4+1] = v.y; L[r][c4+2] = v.z; L[r][c4+3] = v.w;
  }
  __syncthreads();
  #pragma unroll
  for (int m=0;m<4;++m){
    int flat = t + 256*m;
    int oc = flat >> 4, k4 = (flat & 15) << 2;
    ushort4 h4, m4, l4;
    split3(L[k4+0][oc], h4.x, m4.x, l4.x);
    split3(L[k4+1][oc], h4.y, m4.y, l4.y);
    split3(L[k4+2][oc], h4.z, m4.z, l4.z);
    split3(L[k4+3][oc], h4.w, m4.w, l4.w);
    size_t off = (size_t)(bj*64 + oc)*R + bi*64 + k4;
    *(ushort4*)&oh[off] = h4;
    *(ushort4*)&om[off] = m4;
    *(ushort4*)&ol[off] = l4;
  }
}

// ---------------- K1: fused MFMA backbone fv = relu(X@W1+b1)@W2 + b2 ----------------
// 3-way bf16 split, 6 MFMA terms per fragment pair (~f32 accuracy).
// Block: 256 thr (4 waves), 64 rows. nc loop over H in chunks of 128.
// LDS: xsr = 3x[64][128B] (Xs in phase A, A1s halves in phase B) = 24KB
//      wsr = 3x[128][128B] (W1s in phase A, W2s in phase B)      = 48KB
// XOR swizzle: 16B piece p of row r stored at slot p^(r&7); gload uses
// pre-swizzled global source (linear LDS dest), reads apply same XOR.
__global__ __launch_bounds__(256, 2) void k1_mfma(
    const float* __restrict__ X,
    const u16* __restrict__ W1h, const u16* __restrict__ W1m, const u16* __restrict__ W1l,
    const float* __restrict__ b1,
    const u16* __restrict__ W2h, const u16* __restrict__ W2m, const u16* __restrict__ W2l,
    const float* __restrict__ b2, float* __restrict__ fv)
{
  __shared__ __align__(16) unsigned char sm[73728];
  unsigned char* xsr = sm;          // 3 * 8192
  unsigned char* wsr = sm + 24576;  // 3 * 16384

  const int t  = threadIdx.x;
  const int l  = t & 63;
  const int wn = t >> 6;        // wave id -> output col group (wn*32)
  const int g  = (l >> 4) & 3;
  const int lr = l & 15;
  const int row0 = blockIdx.x * 64;

  f32x4 fvacc[4][2];
  #pragma unroll
  for (int mf=0;mf<4;++mf){
    fvacc[mf][0] = (f32x4){0.f,0.f,0.f,0.f};
    fvacc[mf][1] = (f32x4){0.f,0.f,0.f,0.f};
  }

  #pragma unroll 1
  for (int nc = 0; nc < 16; ++nc){
    f32x4 a1acc[4][2];
    #pragma unroll
    for (int mf=0;mf<4;++mf){
      a1acc[mf][0] = (f32x4){0.f,0.f,0.f,0.f};
      a1acc[mf][1] = (f32x4){0.f,0.f,0.f,0.f};
    }

    // ================= Phase A: A1 = X @ W1[:, nc*128 : +128] =================
    #pragma unroll 1
    for (int ks = 0; ks < 12; ++ks){
      // stage Xs: f32 [64][64] -> 3-split bf16, swizzled ds_write
      #pragma unroll
      for (int m=0;m<4;++m){
        const int flat = t + 256*m;
        const int xr = flat >> 4;
        const int c4 = (flat & 15) << 2;
        f32x4 v = *(const f32x4*)&X[(size_t)(row0+xr)*768 + ks*64 + c4];
        ushort4 h4, m4, l4;
        split3(v[0], h4.x, m4.x, l4.x);
        split3(v[1], h4.y, m4.y, l4.y);
        split3(v[2], h4.z, m4.z, l4.z);
        split3(v[3], h4.w, m4.w, l4.w);
        const int bo = xr*128 + ((2*c4) ^ ((xr & 7) << 4));
        *(ushort4*)(xsr + bo)          = h4;
        *(ushort4*)(xsr + 8192 + bo)   = m4;
        *(ushort4*)(xsr + 16384 + bo)  = l4;
      }
      // stage W1s: global_load_lds, 48 chunks of 1KB (12 per wave)
      #pragma unroll
      for (int i=0;i<12;++i){
        const int ci = wn*12 + i;
        const int s  = ci >> 4;
        const int rb = ci & 15;
        const int rloc = rb*8 + (l >> 3);
        const int q  = l & 7;
        const u16* Wp = (s==0) ? W1h : ((s==1) ? W1m : W1l);
        const u16* src = Wp + (size_t)(nc*128 + rloc)*768 + ks*64 + ((q ^ (rloc & 7)) << 3);
        gload16(src, wsr + s*16384 + rb*1024);
      }
      __syncthreads();

      #pragma unroll
      for (int kk=0;kk<2;++kk){
        s16x8 Bf[3][2], Af[3][4];
        #pragma unroll
        for (int s=0;s<3;++s){
          #pragma unroll
          for (int nf=0;nf<2;++nf){
            const int br = wn*32 + nf*16 + lr;
            Bf[s][nf] = *(const s16x8*)(wsr + s*16384 + br*128 + ((16*(g + 4*kk)) ^ ((br & 7) << 4)));
          }
          #pragma unroll
          for (int mf=0;mf<4;++mf){
            const int ar = mf*16 + lr;
            Af[s][mf] = *(const s16x8*)(xsr + s*8192 + ar*128 + ((16*(g + 4*kk)) ^ ((ar & 7) << 4)));
          }
        }
        #pragma unroll
        for (int mf=0;mf<4;++mf){
          #pragma unroll
          for (int nf=0;nf<2;++nf){
            f32x4 acc = a1acc[mf][nf];
            acc = MFMA16(Af[0][mf], Bf[0][nf], acc);
            acc = MFMA16(Af[0][mf], Bf[1][nf], acc);
            acc = MFMA16(Af[1][mf], Bf[0][nf], acc);
            acc = MFMA16(Af[1][mf], Bf[1][nf], acc);
            acc = MFMA16(Af[0][mf], Bf[2][nf], acc);
            acc = MFMA16(Af[2][mf], Bf[0][nf], acc);
            a1acc[mf][nf] = acc;
          }
        }
      }
      __syncthreads();
    }

    // ================= Phase B: fv += relu(A1+b1) @ W2[nc chunk] =================
    const float b1v0 = b1[nc*128 + wn*32 + lr];
    const float b1v1 = b1[nc*128 + wn*32 + 16 + lr];

    #pragma unroll
    for (int half=0; half<2; ++half){
      // waves {2*half, 2*half+1} own A1 cols [half*64, half*64+64): write A1s
      if ((wn >> 1) == half){
        #pragma unroll
        for (int mf=0;mf<4;++mf){
          #pragma unroll
          for (int nf=0;nf<2;++nf){
            const int klocal = (wn & 1)*32 + nf*16 + lr;
            #pragma unroll
            for (int r=0;r<4;++r){
              float vv = a1acc[mf][nf][r] + ((nf==0) ? b1v0 : b1v1);
              vv = vv > 0.f ? vv : 0.f;
              u16 sh, sm2, sl;
              split3(vv, sh, sm2, sl);
              const int ar = mf*16 + g*4 + r;
              const int bo = ar*128 + ((2*klocal) ^ ((ar & 7) << 4));
              *(u16*)(xsr + bo)         = sh;
              *(u16*)(xsr + 8192 + bo)  = sm2;
              *(u16*)(xsr + 16384 + bo) = sl;
            }
          }
        }
      }
      // stage W2s [128 n][64 k] x3 splits
      #pragma unroll
      for (int i=0;i<12;++i){
        const int ci = wn*12 + i;
        const int s  = ci >> 4;
        const int rb = ci & 15;
        const int rloc = rb*8 + (l >> 3);
        const int q  = l & 7;
        const u16* Wp = (s==0) ? W2h : ((s==1) ? W2m : W2l);
        const u16* src = Wp + (size_t)rloc*2048 + nc*128 + half*64 + ((q ^ (rloc & 7)) << 3);
        gload16(src, wsr + s*16384 + rb*1024);
      }
      __syncthreads();

      #pragma unroll
      for (int kk=0;kk<2;++kk){
        s16x8 Bf[3][2], Af[3][4];
        #pragma unroll
        for (int s=0;s<3;++s){
          #pragma unroll
          for (int nf=0;nf<2;++nf){
            const int br = wn*32 + nf*16 + lr;
            Bf[s][nf] = *(const s16x8*)(wsr + s*16384 + br*128 + ((16*(g + 4*kk)) ^ ((br & 7) << 4)));
          }
          #pragma unroll
          for (int mf=0;mf<4;++mf){
            const int ar = mf*16 + lr;
            Af[s][mf] = *(const s16x8*)(xsr + s*8192 + ar*128 + ((16*(g + 4*kk)) ^ ((ar & 7) << 4)));
          }
        }
        #pragma unroll
        for (int mf=0;mf<4;++mf){
          #pragma unroll
          for (int nf=0;nf<2;++nf){
            f32x4 acc = fvacc[mf][nf];
            acc = MFMA16(Af[0][mf], Bf[0][nf], acc);
            acc = MFMA16(Af[0][mf], Bf[1][nf], acc);
            acc = MFMA16(Af[1][mf], Bf[0][nf], acc);
            acc = MFMA16(Af[1][mf], Bf[1][nf], acc);
            acc = MFMA16(Af[0][mf], Bf[2][nf], acc);
            acc = MFMA16(Af[2][mf], Bf[0][nf], acc);
            fvacc[mf][nf] = acc;
          }
        }
      }
      __syncthreads();
    }
  }

  // epilogue: fv = fvacc + b2
  const float b2v0 = b2[wn*32 + lr];
  const float b2v1 = b2[wn*32 + 16 + lr];
  #pragma unroll
  for (int mf=0;mf<4;++mf){
    #pragma unroll
    for (int nf=0;nf<2;++nf){
      #pragma unroll
      for (int r=0;r<4;++r){
        const int frow = row0 + mf*16 + g*4 + r;
        const int col  = wn*32 + nf*16 + lr;
        fv[(size_t)frow*NZ + col] = fvacc[mf][nf][r] + ((nf==0) ? b2v0 : b2v1);
      }
    }
  }
}

// ---------------- K2: dist -> Q0 = exp(-2*dist), row-major [BN][NCN] ----------------
__global__ __launch_bounds__(256) void k2_dist(
    const float* __restrict__ fv, const float* __restrict__ cent,
    float* __restrict__ Q0)
{
  __shared__ __align__(16) float fvs[32*128];
  __shared__ __align__(16) float cs[64*128];
  __shared__ float fvn[32];
  __shared__ float cn[64];
  const int t = threadIdx.x;
  const int tx = t & 15, ty = t >> 4;
  const int row0 = blockIdx.x * 32;

  #pragma unroll
  for (int m=0;m<4;++m){
    int idx4 = t + 256*m;
    int r  = idx4 >> 5;
    int c4 = (idx4 & 31) << 2;
    *(float4*)&fvs[r*128 + (c4 ^ ((((r>>1)&7))<<2))] =
        *(const float4*)&fv[(size_t)(row0 + r)*NZ + c4];
  }
  __syncthreads();
  if (t < 32){
    int xw = ((t>>1)&7)<<2;
    float s = 0.f;
    for (int z=0;z<NZ;z+=4){
      const float4 v = *(const float4*)&fvs[t*128 + (z ^ xw)];
      s += v.x*v.x; s += v.y*v.y; s += v.z*v.z; s += v.w*v.w;
    }
    fvn[t] = s;
  }

  for (int cc = 0; cc < NCN; cc += 64){
    #pragma unroll
    for (int m=0;m<8;++m){
      int idx4 = t + 256*m;
      int r  = idx4 >> 5;
      int c4 = (idx4 & 31) << 2;
      *(float4*)&cs[r*128 + (c4 ^ ((((r>>3)&7))<<2))] =
          *(const float4*)&cent[(size_t)(cc + r)*NZ + c4];
    }
    __syncthreads();
    if (t < 64){
      int xw = ((t>>3)&7)<<2;
      float s = 0.f;
      for (int z=0;z<NZ;z+=4){
        const float4 v = *(const float4*)&cs[t*128 + (z ^ xw)];
        s += v.x*v.x; s += v.y*v.y; s += v.z*v.z; s += v.w*v.w;
      }
      cn[t] = s;
    }
    __syncthreads();

    float acc[2][4];
    #pragma unroll
    for (int i=0;i<2;++i)
      #pragma unroll
      for (int j=0;j<4;++j) acc[i][j]=0.f;

    const int xwf = (ty&7)<<2;
    const int xwc = ((tx>>1)&7)<<2;
    #pragma unroll 4
    for (int kk=0; kk<NZ; kk+=4){
      float4 fq0 = *(const float4*)&fvs[(2*ty+0)*128 + (kk ^ xwf)];
      float4 fq1 = *(const float4*)&fvs[(2*ty+1)*128 + (kk ^ xwf)];
      float4 cb[4];
      #pragma unroll
      for (int j=0;j<4;++j)
        cb[j] = *(const float4*)&cs[(4*tx+j)*128 + (kk ^ xwc)];
      #pragma unroll
      for (int j=0;j<4;++j){
        acc[0][j] += fq0.x*cb[j].x; acc[0][j] += fq0.y*cb[j].y;
        acc[0][j] += fq0.z*cb[j].z; acc[0][j] += fq0.w*cb[j].w;
        acc[1][j] += fq1.x*cb[j].x; acc[1][j] += fq1.y*cb[j].y;
        acc[1][j] += fq1.z*cb[j].z; acc[1][j] += fq1.w*cb[j].w;
      }
    }
    #pragma unroll
    for (int i=0;i<2;++i){
      int row = row0 + 2*ty + i;
      float fnv = fvn[2*ty+i];
      float o[4];
      #pragma unroll
      for (int j=0;j<4;++j){
        float sq = fnv + cn[4*tx+j] - 2.0f*acc[i][j];
        sq = sq > 1e-12f ? sq : 1e-12f;
        float d = sqrtf(sq);
        o[j] = expf(-2.0f*d);
      }
      float4 ov; ov.x=o[0]; ov.y=o[1]; ov.z=o[2]; ov.w=o[3];
      *(float4*)&Q0[(size_t)row*NCN + cc + 4*tx] = ov;
    }
    __syncthreads();
  }
}

// ---------------- K3: one fused sinkhorn pass ----------------
__global__ __launch_bounds__(256) void k3_pass(
    const float* __restrict__ Q0, const float* __restrict__ u,
    float* __restrict__ S_part, float alpha)
{
  __shared__ __align__(16) float ul[NCN];
  __shared__ __align__(16) float Sw[4][NCN];
  const int t = threadIdx.x;
  const int w = t >> 6, l = t & 63;
  #pragma unroll
  for (int m=0;m<4;++m) ul[t + 256*m] = u[t + 256*m];
  #pragma unroll
  for (int m=0;m<16;++m) (&Sw[0][0])[t + 256*m] = 0.f;
  __syncthreads();

  const float4* ul4 = (const float4*)ul;
  float4* Sw4 = (float4*)&Sw[w][0];
  const int gw = blockIdx.x*4 + w;
  const size_t b0 = (size_t)gw * 16;
  for (int rr=0; rr<16; ++rr){
    const float4* qrow = (const float4*)(Q0 + (b0 + rr)*NCN);
    float4 q4[4];
    float part = 0.f;
    #pragma unroll
    for (int j=0;j<4;++j){
      q4[j] = qrow[l + 64*j];
      float4 uu = ul4[l + 64*j];
      part += q4[j].x*uu.x; part += q4[j].y*uu.y;
      part += q4[j].z*uu.z; part += q4[j].w*uu.w;
    }
    #pragma unroll
    for (int off=32; off; off>>=1) part += __shfl_xor(part, off, 64);
    const float v = alpha / part;
    #pragma unroll
    for (int j=0;j<4;++j){
      float4 s = Sw4[l + 64*j];
      s.x += q4[j].x*v; s.y += q4[j].y*v; s.z += q4[j].z*v; s.w += q4[j].w*v;
      Sw4[l + 64*j] = s;
    }
  }
  __syncthreads();
  #pragma unroll
  for (int m=0;m<4;++m){
    int k = t + 256*m;
    S_part[(size_t)blockIdx.x*NCN + k] = ((Sw[0][k]+Sw[1][k])+(Sw[2][k]+Sw[3][k]));
  }
}

// ---------------- K4: u = r / colsum(S_part), parallel ----------------
__global__ __launch_bounds__(256) void k4_unew(
    const float* __restrict__ S_part, float* __restrict__ u)
{
  __shared__ float P[4][64];
  const int t = threadIdx.x;
  const int col = blockIdx.x*64 + (t & 63);
  const int s4 = t >> 6;
  float p = 0.f;
  for (int i=0;i<128;++i)
    p += S_part[(size_t)(s4*128 + i)*NCN + col];
  P[s4][t & 63] = p;
  __syncthreads();
  if (s4 == 0){
    float tot = ((P[0][t] + P[1][t]) + (P[2][t] + P[3][t]));
    u[col] = (1.0f/1024.0f) / tot;
  }
}

// ---------------- K5: final pass ----------------
__device__ __forceinline__ float comp4(const float4 v, int c){
  return (c==0)?v.x:(c==1)?v.y:(c==2)?v.z:v.w;
}

__global__ __launch_bounds__(256) void k5_final(
    const float* __restrict__ Q0, const float* __restrict__ u,
    float* __restrict__ softc_part, float* __restrict__ loss_part,
    int* __restrict__ hist_raw, int* __restrict__ hist_clu,
    float* __restrict__ out_ba)
{
  __shared__ __align__(16) float ul[NCN];
  __shared__ __align__(16) float Sw[4][NCN];
  __shared__ float lossw[4];
  const int t = threadIdx.x;
  const int w = t >> 6, l = t & 63;
  #pragma unroll
  for (int m=0;m<4;++m) ul[t + 256*m] = u[t + 256*m];
  #pragma unroll
  for (int m=0;m<16;++m) (&Sw[0][0])[t + 256*m] = 0.f;
  __syncthreads();

  const float4* ul4 = (const float4*)ul;
  float4* Sw4 = (float4*)&Sw[w][0];
  const int gw = blockIdx.x*4 + w;
  const size_t b0 = (size_t)gw * 32;
  float lacc = 0.f;
  for (int rr=0; rr<32; ++rr){
    const size_t b = b0 + rr;
    const float4* qrow = (const float4*)(Q0 + b*NCN);
    float4 q4[4], wv4[4];
    float part = 0.f;
    #pragma unroll
    for (int j=0;j<4;++j){
      q4[j] = qrow[l + 64*j];
      float4 uu = ul4[l + 64*j];
      wv4[j].x = uu.x*q4[j].x; wv4[j].y = uu.y*q4[j].y;
      wv4[j].z = uu.z*q4[j].z; wv4[j].w = uu.w*q4[j].w;
      part += wv4[j].x; part += wv4[j].y; part += wv4[j].z; part += wv4[j].w;
    }
    #pragma unroll
    for (int off=32; off; off>>=1) part += __shfl_xor(part, off, 64);
    const float inv = 1.0f / part;

    float smin = wv4[0].x * inv; int kmin = 4*l; float qat = q4[0].x;
    float qmax = q4[0].x;        int kmax = 4*l;
    #pragma unroll
    for (int j=0;j<4;++j){
      #pragma unroll
      for (int c=0;c<4;++c){
        if (j==0 && c==0) continue;
        float qv = comp4(q4[j], c);
        float sv = comp4(wv4[j], c) * inv;
        int k = 4*l + 256*j + c;
        if (sv < smin){ smin = sv; kmin = k; qat = qv; }
        if (qv > qmax){ qmax = qv; kmax = k; }
      }
    }
    #pragma unroll
    for (int off=32; off; off>>=1){
      float s2 = __shfl_xor(smin, off, 64);
      int   k2 = __shfl_xor(kmin, off, 64);
      float q2 = __shfl_xor(qat,  off, 64);
      if (s2 < smin || (s2 == smin && k2 < kmin)){ smin=s2; kmin=k2; qat=q2; }
      float m2 = __shfl_xor(qmax, off, 64);
      int   i2 = __shfl_xor(kmax, off, 64);
      if (m2 > qmax || (m2 == qmax && i2 < kmax)){ qmax=m2; kmax=i2; }
    }
    #pragma unroll
    for (int j=0;j<4;++j){
      float4 s = Sw4[l + 64*j];
      s.x += wv4[j].x*inv; s.y += wv4[j].y*inv;
      s.z += wv4[j].z*inv; s.w += wv4[j].w*inv;
      Sw4[l + 64*j] = s;
    }
    if (l == 0){
      out_ba[b] = (float)kmin;
      atomicAdd(&hist_clu[kmin], 1);
      atomicAdd(&hist_raw[kmax], 1);
      lacc += -0.5f * logf(qat);
    }
  }
  if (l == 0) lossw[w] = lacc;
  __syncthreads();
  #pragma unroll
  for (int m=0;m<4;++m){
    int k = t + 256*m;
    softc_part[(size_t)blockIdx.x*NCN + k] = ((Sw[0][k]+Sw[1][k])+(Sw[2][k]+Sw[3][k]));
  }
  if (t == 0) loss_part[blockIdx.x] = ((lossw[0]+lossw[1])+(lossw[2]+lossw[3]));
}

// ---------------- K6: deterministic combine + output write ----------------
__global__ __launch_bounds__(1024) void k6_fin(
    const float* __restrict__ softc_part, const float* __restrict__ loss_part,
    const int* __restrict__ hist_raw, const int* __restrict__ hist_clu,
    const int* __restrict__ raw_in, const int* __restrict__ clu_in,
    const float* __restrict__ tsoft_in, float* __restrict__ out)
{
  const int k = threadIdx.x;
  float s0=0.f,s1=0.f,s2=0.f,s3=0.f;
  for (int blk=0; blk<256; blk+=4){
    s0 += softc_part[(size_t)(blk+0)*NCN + k];
    s1 += softc_part[(size_t)(blk+1)*NCN + k];
    s2 += softc_part[(size_t)(blk+2)*NCN + k];
    s3 += softc_part[(size_t)(blk+3)*NCN + k];
  }
  const float s = ((s0+s1)+(s2+s3));
  out[1 + BN + k]           = s;
  out[1 + BN + NCN + k]     = (float)(raw_in[k] + hist_raw[k]);
  out[1 + BN + 2*NCN + k]   = (float)(clu_in[k] + hist_clu[k]);
  out[1 + BN + 3*NCN + k]   = tsoft_in[k] + s;
  if (k == 0){
    float ls = 0.f;
    for (int i=0;i<256;++i) ls += loss_part[i];
    out[0] = ls / 32768.0f;
  }
}

extern "C" void kernel_launch(void* const* d_in, const int* in_sizes, int n_in,
                              void* d_out, int out_size, void* d_ws, size_t ws_size,
                              hipStream_t stream) {
  (void)in_sizes; (void)n_in; (void)out_size; (void)ws_size;
  const float* x      = (const float*)d_in[0];
  const float* W1     = (const float*)d_in[1];
  const float* b1     = (const float*)d_in[2];
  const float* W2     = (const float*)d_in[3];
  const float* b2     = (const float*)d_in[4];
  const float* cent   = (const float*)d_in[5];
  const int*   clu_in = (const int*)d_in[6];
  const int*   raw_in = (const int*)d_in[7];
  const float* tsoft  = (const float*)d_in[8];
  float* out = (float*)d_out;

  // ws layout (float units):
  float* ws        = (float*)d_ws;
  float* fv        = ws;                      // 4194304
  float* Q0        = ws + 4194304;            // 33554432
  float* u         = Q0 + 33554432;           // 1024
  float* S_part    = u + 1024;                // 524288
  float* softc_par = S_part + 524288;         // 262144
  float* loss_par  = softc_par + 262144;      // 256
  int*   hist_raw  = (int*)(loss_par + 256);  // 1024 ints
  int*   hist_clu  = hist_raw + 1024;         // 1024 ints
  // split weight arrays (u16), 16B-aligned
  u16* W1Th = (u16*)(ws + 38538496);
  u16* W1Tm = W1Th + 1572864;
  u16* W1Tl = W1Tm + 1572864;
  u16* W2Th = W1Tl + 1572864;
  u16* W2Tm = W2Th + 262144;
  u16* W2Tl = W2Tm + 262144;

  c_tsplit<<<dim3(12, 32), 256, 0, stream>>>(W1, 768, 2048, W1Th, W1Tm, W1Tl);
  c_tsplit<<<dim3(32, 2),  256, 0, stream>>>(W2, 2048, 128, W2Th, W2Tm, W2Tl);
  k0_init<<<1, 1024, 0, stream>>>(u, hist_raw, hist_clu);
  k1_mfma<<<512, 256, 0, stream>>>(x, W1Th, W1Tm, W1Tl, b1, W2Th, W2Tm, W2Tl, b2, fv);
  k2_dist<<<1024, 256, 0, stream>>>(fv, cent, Q0);
  for (int it = 0; it < 15; ++it){
    const float alpha = (it == 0) ? 1.0f : (1.0f/32768.0f);
    k3_pass<<<512, 256, 0, stream>>>(Q0, u, S_part, alpha);
    k4_unew<<<16, 256, 0, stream>>>(S_part, u);
  }
  k5_final<<<256, 256, 0, stream>>>(Q0, u, softc_par, loss_par,
                                    hist_raw, hist_clu, out + 1);
  k6_fin<<<1, 1024, 0, stream>>>(softc_par, loss_par, hist_raw, hist_clu,
                                 raw_in, clu_in, tsoft, out);
}

// Round 3
// 1317.183 us; speedup vs baseline: 2.5963x; 1.1016x over previous
//
#include <hip/hip_runtime.h>
#include <math.h>

// Problem constants (B, D_IN, H, NZ, NC)
#define BN    32768
#define DIN   768
#define HN    2048
#define NZ    128
#define NCN   1024

typedef __attribute__((ext_vector_type(8))) short s16x8;
typedef __attribute__((ext_vector_type(4))) float f32x4;
typedef unsigned short u16;

#define MFMA16(a,b,c) __builtin_amdgcn_mfma_f32_16x16x32_bf16(a,b,c,0,0,0)

__device__ __forceinline__ u16 bf16_rne(float x){
  unsigned u = __float_as_uint(x);
  unsigned r = (u + 0x7FFFu + ((u >> 16) & 1u)) >> 16;
  return (u16)r;
}
__device__ __forceinline__ float bf16_tof(u16 h){
  return __uint_as_float(((unsigned)h) << 16);
}
__device__ __forceinline__ void split3(float x, u16& h, u16& m, u16& l){
  h = bf16_rne(x);
  float r1 = x - bf16_tof(h);
  m = bf16_rne(r1);
  float r2 = r1 - bf16_tof(m);
  l = bf16_rne(r2);
}

__device__ __forceinline__ void gload16(const void* gsrc, void* lds){
  __builtin_amdgcn_global_load_lds(
      (const __attribute__((address_space(1))) unsigned int*)gsrc,
      (__attribute__((address_space(3))) unsigned int*)lds, 16, 0, 0);
}

// ---------------- K0: init (u=1, histograms=0) ----------------
__global__ __launch_bounds__(1024) void k0_init(float* u, int* hraw, int* hclu){
  const int k = threadIdx.x;
  u[k] = 1.0f;
  hraw[k] = 0;
  hclu[k] = 0;
}

// ---------------- Convert: elementwise 3-way bf16 split (layout preserved) ----
__global__ __launch_bounds__(256) void c_split(
    const float* __restrict__ in, u16* __restrict__ oh, u16* __restrict__ om,
    u16* __restrict__ ol, int n4)
{
  const int i = blockIdx.x*256 + threadIdx.x;
  if (i >= n4) return;
  const f32x4 v = *(const f32x4*)&in[(size_t)i*4];
  ushort4 h4, m4, l4;
  split3(v[0], h4.x, m4.x, l4.x);
  split3(v[1], h4.y, m4.y, l4.y);
  split3(v[2], h4.z, m4.z, l4.z);
  split3(v[3], h4.w, m4.w, l4.w);
  *(ushort4*)&oh[(size_t)i*4] = h4;
  *(ushort4*)&om[(size_t)i*4] = m4;
  *(ushort4*)&ol[(size_t)i*4] = l4;
}

// ---------------- Convert: transpose + 3-way bf16 split ----------------
// in [R][C] f32 -> oh/om/ol [C][R] bf16(u16)
__global__ __launch_bounds__(256) void c_tsplit(
    const float* __restrict__ in, int R, int C,
    u16* __restrict__ oh, u16* __restrict__ om, u16* __restrict__ ol)
{
  __shared__ float L[64][65];
  const int t = threadIdx.x;
  const int bi = blockIdx.x, bj = blockIdx.y;
  #pragma unroll
  for (int m=0;m<4;++m){
    int flat = t + 256*m;
    int r = flat >> 4, c4 = (flat & 15) << 2;
    const float4 v = *(const float4*)&in[(size_t)(bi*64 + r)*C + bj*64 + c4];
    L[r][c4+0] = v.x; L[r][c4+1] = v.y; L[r][c4+2] = v.z; L[r][c4+3] = v.w;
  }
  __syncthreads();
  #pragma unroll
  for (int m=0;m<4;++m){
    int flat = t + 256*m;
    int oc = flat >> 4, k4 = (flat & 15) << 2;
    ushort4 h4, m4, l4;
    split3(L[k4+0][oc], h4.x, m4.x, l4.x);
    split3(L[k4+1][oc], h4.y, m4.y, l4.y);
    split3(L[k4+2][oc], h4.z, m4.z, l4.z);
    split3(L[k4+3][oc], h4.w, m4.w, l4.w);
    size_t off = (size_t)(bj*64 + oc)*R + bi*64 + k4;
    *(ushort4*)&oh[off] = h4;
    *(ushort4*)&om[off] = m4;
    *(ushort4*)&ol[off] = l4;
  }
}

// ---------------- Convert: row sum-of-squares, rows of 128 ----------------
__global__ __launch_bounds__(256) void c_norm(
    const float* __restrict__ in, float* __restrict__ out)
{
  const int w = threadIdx.x >> 6, l = threadIdx.x & 63;
  const int row = blockIdx.x*4 + w;
  const float2 v = *(const float2*)&in[(size_t)row*128 + l*2];
  float s = v.x*v.x + v.y*v.y;
  #pragma unroll
  for (int off=32; off; off>>=1) s += __shfl_xor(s, off, 64);
  if (l == 0) out[row] = s;
}

// ---------------- K1: fused MFMA backbone fv = relu(X@W1+b1)@W2 + b2 ----------------
// 3-way bf16 split, 6 MFMA terms per fragment pair (~f32 accuracy).
// X pre-split in global (Xh/Xm/Xl) -> phase A staging is pure global_load_lds.
__global__ __launch_bounds__(256, 2) void k1_mfma(
    const u16* __restrict__ Xh, const u16* __restrict__ Xm, const u16* __restrict__ Xl,
    const u16* __restrict__ W1h, const u16* __restrict__ W1m, const u16* __restrict__ W1l,
    const float* __restrict__ b1,
    const u16* __restrict__ W2h, const u16* __restrict__ W2m, const u16* __restrict__ W2l,
    const float* __restrict__ b2, float* __restrict__ fv)
{
  __shared__ __align__(16) unsigned char sm[73728];
  unsigned char* xsr = sm;          // 3 * 8192
  unsigned char* wsr = sm + 24576;  // 3 * 16384

  const int t  = threadIdx.x;
  const int l  = t & 63;
  const int wn = t >> 6;        // wave id -> output col group (wn*32)
  const int g  = (l >> 4) & 3;
  const int lr = l & 15;
  const int row0 = blockIdx.x * 64;

  f32x4 fvacc[4][2];
  #pragma unroll
  for (int mf=0;mf<4;++mf){
    fvacc[mf][0] = (f32x4){0.f,0.f,0.f,0.f};
    fvacc[mf][1] = (f32x4){0.f,0.f,0.f,0.f};
  }

  #pragma unroll 1
  for (int nc = 0; nc < 16; ++nc){
    f32x4 a1acc[4][2];
    #pragma unroll
    for (int mf=0;mf<4;++mf){
      a1acc[mf][0] = (f32x4){0.f,0.f,0.f,0.f};
      a1acc[mf][1] = (f32x4){0.f,0.f,0.f,0.f};
    }

    // ================= Phase A: A1 = X @ W1[:, nc*128 : +128] =================
    #pragma unroll 1
    for (int ks = 0; ks < 12; ++ks){
      // stage Xs: pre-split bf16, global_load_lds (6 chunks of 1KB per wave)
      #pragma unroll
      for (int i=0;i<6;++i){
        const int ci = wn*6 + i;          // 0..23
        const int s  = ci >> 3;
        const int rb = ci & 7;
        const int xr = rb*8 + (l >> 3);
        const int q  = l & 7;
        const u16* Xp = (s==0) ? Xh : ((s==1) ? Xm : Xl);
        const u16* src = Xp + (size_t)(row0 + xr)*768 + ks*64 + ((q ^ (xr & 7)) << 3);
        gload16(src, xsr + s*8192 + rb*1024);
      }
      // stage W1s: global_load_lds, 48 chunks of 1KB (12 per wave)
      #pragma unroll
      for (int i=0;i<12;++i){
        const int ci = wn*12 + i;
        const int s  = ci >> 4;
        const int rb = ci & 15;
        const int rloc = rb*8 + (l >> 3);
        const int q  = l & 7;
        const u16* Wp = (s==0) ? W1h : ((s==1) ? W1m : W1l);
        const u16* src = Wp + (size_t)(nc*128 + rloc)*768 + ks*64 + ((q ^ (rloc & 7)) << 3);
        gload16(src, wsr + s*16384 + rb*1024);
      }
      __syncthreads();

      #pragma unroll
      for (int kk=0;kk<2;++kk){
        s16x8 Bf[3][2], Af[3][4];
        #pragma unroll
        for (int s=0;s<3;++s){
          #pragma unroll
          for (int nf=0;nf<2;++nf){
            const int br = wn*32 + nf*16 + lr;
            Bf[s][nf] = *(const s16x8*)(wsr + s*16384 + br*128 + ((16*(g + 4*kk)) ^ ((br & 7) << 4)));
          }
          #pragma unroll
          for (int mf=0;mf<4;++mf){
            const int ar = mf*16 + lr;
            Af[s][mf] = *(const s16x8*)(xsr + s*8192 + ar*128 + ((16*(g + 4*kk)) ^ ((ar & 7) << 4)));
          }
        }
        #pragma unroll
        for (int mf=0;mf<4;++mf){
          #pragma unroll
          for (int nf=0;nf<2;++nf){
            f32x4 acc = a1acc[mf][nf];
            acc = MFMA16(Af[0][mf], Bf[0][nf], acc);
            acc = MFMA16(Af[0][mf], Bf[1][nf], acc);
            acc = MFMA16(Af[1][mf], Bf[0][nf], acc);
            acc = MFMA16(Af[1][mf], Bf[1][nf], acc);
            acc = MFMA16(Af[0][mf], Bf[2][nf], acc);
            acc = MFMA16(Af[2][mf], Bf[0][nf], acc);
            a1acc[mf][nf] = acc;
          }
        }
      }
      __syncthreads();
    }

    // ================= Phase B: fv += relu(A1+b1) @ W2[nc chunk] =================
    const float b1v0 = b1[nc*128 + wn*32 + lr];
    const float b1v1 = b1[nc*128 + wn*32 + 16 + lr];

    #pragma unroll
    for (int half=0; half<2; ++half){
      // waves {2*half, 2*half+1} own A1 cols [half*64, half*64+64): write A1s
      if ((wn >> 1) == half){
        #pragma unroll
        for (int mf=0;mf<4;++mf){
          #pragma unroll
          for (int nf=0;nf<2;++nf){
            const int klocal = (wn & 1)*32 + nf*16 + lr;
            #pragma unroll
            for (int r=0;r<4;++r){
              float vv = a1acc[mf][nf][r] + ((nf==0) ? b1v0 : b1v1);
              vv = vv > 0.f ? vv : 0.f;
              u16 sh, sm2, sl;
              split3(vv, sh, sm2, sl);
              const int ar = mf*16 + g*4 + r;
              const int bo = ar*128 + ((2*klocal) ^ ((ar & 7) << 4));
              *(u16*)(xsr + bo)         = sh;
              *(u16*)(xsr + 8192 + bo)  = sm2;
              *(u16*)(xsr + 16384 + bo) = sl;
            }
          }
        }
      }
      // stage W2s [128 n][64 k] x3 splits
      #pragma unroll
      for (int i=0;i<12;++i){
        const int ci = wn*12 + i;
        const int s  = ci >> 4;
        const int rb = ci & 15;
        const int rloc = rb*8 + (l >> 3);
        const int q  = l & 7;
        const u16* Wp = (s==0) ? W2h : ((s==1) ? W2m : W2l);
        const u16* src = Wp + (size_t)rloc*2048 + nc*128 + half*64 + ((q ^ (rloc & 7)) << 3);
        gload16(src, wsr + s*16384 + rb*1024);
      }
      __syncthreads();

      #pragma unroll
      for (int kk=0;kk<2;++kk){
        s16x8 Bf[3][2], Af[3][4];
        #pragma unroll
        for (int s=0;s<3;++s){
          #pragma unroll
          for (int nf=0;nf<2;++nf){
            const int br = wn*32 + nf*16 + lr;
            Bf[s][nf] = *(const s16x8*)(wsr + s*16384 + br*128 + ((16*(g + 4*kk)) ^ ((br & 7) << 4)));
          }
          #pragma unroll
          for (int mf=0;mf<4;++mf){
            const int ar = mf*16 + lr;
            Af[s][mf] = *(const s16x8*)(xsr + s*8192 + ar*128 + ((16*(g + 4*kk)) ^ ((ar & 7) << 4)));
          }
        }
        #pragma unroll
        for (int mf=0;mf<4;++mf){
          #pragma unroll
          for (int nf=0;nf<2;++nf){
            f32x4 acc = fvacc[mf][nf];
            acc = MFMA16(Af[0][mf], Bf[0][nf], acc);
            acc = MFMA16(Af[0][mf], Bf[1][nf], acc);
            acc = MFMA16(Af[1][mf], Bf[0][nf], acc);
            acc = MFMA16(Af[1][mf], Bf[1][nf], acc);
            acc = MFMA16(Af[0][mf], Bf[2][nf], acc);
            acc = MFMA16(Af[2][mf], Bf[0][nf], acc);
            fvacc[mf][nf] = acc;
          }
        }
      }
      __syncthreads();
    }
  }

  // epilogue: fv = fvacc + b2
  const float b2v0 = b2[wn*32 + lr];
  const float b2v1 = b2[wn*32 + 16 + lr];
  #pragma unroll
  for (int mf=0;mf<4;++mf){
    #pragma unroll
    for (int nf=0;nf<2;++nf){
      #pragma unroll
      for (int r=0;r<4;++r){
        const int frow = row0 + mf*16 + g*4 + r;
        const int col  = wn*32 + nf*16 + lr;
        fv[(size_t)frow*NZ + col] = fvacc[mf][nf][r] + ((nf==0) ? b2v0 : b2v1);
      }
    }
  }
}

// ---------------- K2: MFMA cdist -> Q0 = exp(-2*dist), row-major [BN][NCN] -------
// A (fv splits) in registers (K=128 whole), B (cent splits) staged per 64-chunk.
__global__ __launch_bounds__(256, 2) void k2_mfma(
    const u16* __restrict__ fvh, const u16* __restrict__ fvm, const u16* __restrict__ fvl,
    const u16* __restrict__ ch,  const u16* __restrict__ cm,  const u16* __restrict__ cl,
    const float* __restrict__ fvn, const float* __restrict__ cn,
    float* __restrict__ Q0)
{
  __shared__ __align__(16) unsigned char bs[49152];   // 3 x 16 KB
  __shared__ float cnl[NCN];
  const int t  = threadIdx.x;
  const int l  = t & 63;
  const int wn = t >> 6;
  const int g  = (l >> 4) & 3;
  const int lr = l & 15;
  const int row0 = blockIdx.x * 64;
  const int arow = row0 + wn*16 + lr;

  // A fragments in registers: 3 splits x 4 k-steps
  s16x8 Af[3][4];
  #pragma unroll
  for (int kk=0;kk<4;++kk){
    const size_t ao = (size_t)arow*128 + kk*32 + g*8;
    Af[0][kk] = *(const s16x8*)&fvh[ao];
    Af[1][kk] = *(const s16x8*)&fvm[ao];
    Af[2][kk] = *(const s16x8*)&fvl[ao];
  }
  #pragma unroll
  for (int m=0;m<4;++m) cnl[t + 256*m] = cn[t + 256*m];
  const f32x4 fvnv = *(const f32x4*)&fvn[row0 + wn*16 + g*4];

  #pragma unroll 1
  for (int cc = 0; cc < NCN; cc += 64){
    // stage B: 48 chunks of 1KB (12 per wave), pre-swizzled source
    #pragma unroll
    for (int i=0;i<12;++i){
      const int ci = wn*12 + i;
      const int s  = ci >> 4;
      const int rb = ci & 15;
      const int crow = rb*4 + (l >> 4);
      const int q  = l & 15;
      const u16* Cp = (s==0) ? ch : ((s==1) ? cm : cl);
      const u16* src = Cp + (size_t)(cc + crow)*128 + ((q ^ (crow & 15)) << 3);
      gload16(src, bs + s*16384 + rb*1024);
    }
    __syncthreads();

    f32x4 acc[4];
    #pragma unroll
    for (int nf=0;nf<4;++nf) acc[nf] = (f32x4){0.f,0.f,0.f,0.f};

    #pragma unroll
    for (int kk=0;kk<4;++kk){
      s16x8 Bq[3][4];
      #pragma unroll
      for (int nf=0;nf<4;++nf){
        const int br = nf*16 + lr;
        const int base = br*256 + (((g + 4*kk) ^ (br & 15)) << 4);
        Bq[0][nf] = *(const s16x8*)(bs + base);
        Bq[1][nf] = *(const s16x8*)(bs + 16384 + base);
        Bq[2][nf] = *(const s16x8*)(bs + 32768 + base);
      }
      #pragma unroll
      for (int nf=0;nf<4;++nf){
        f32x4 a = acc[nf];
        a = MFMA16(Af[0][kk], Bq[0][nf], a);
        a = MFMA16(Af[0][kk], Bq[1][nf], a);
        a = MFMA16(Af[1][kk], Bq[0][nf], a);
        a = MFMA16(Af[1][kk], Bq[1][nf], a);
        a = MFMA16(Af[0][kk], Bq[2][nf], a);
        a = MFMA16(Af[2][kk], Bq[0][nf], a);
        acc[nf] = a;
      }
    }

    // epilogue: sq -> sqrt -> exp(-2d) -> Q0
    #pragma unroll
    for (int nf=0;nf<4;++nf){
      const int n = cc + nf*16 + lr;
      const float cv = cnl[n];
      #pragma unroll
      for (int r=0;r<4;++r){
        float sq = fvnv[r] + cv - 2.0f*acc[nf][r];
        sq = sq > 1e-12f ? sq : 1e-12f;
        const float d = sqrtf(sq);
        Q0[(size_t)(row0 + wn*16 + g*4 + r)*NCN + n] = expf(-2.0f*d);
      }
    }
    __syncthreads();
  }
}

// ---------------- K3: one fused sinkhorn pass ----------------
__global__ __launch_bounds__(256) void k3_pass(
    const float* __restrict__ Q0, const float* __restrict__ u,
    float* __restrict__ S_part, float alpha)
{
  __shared__ __align__(16) float ul[NCN];
  __shared__ __align__(16) float Sw[4][NCN];
  const int t = threadIdx.x;
  const int w = t >> 6, l = t & 63;
  #pragma unroll
  for (int m=0;m<4;++m) ul[t + 256*m] = u[t + 256*m];
  #pragma unroll
  for (int m=0;m<16;++m) (&Sw[0][0])[t + 256*m] = 0.f;
  __syncthreads();

  const float4* ul4 = (const float4*)ul;
  float4* Sw4 = (float4*)&Sw[w][0];
  const int gw = blockIdx.x*4 + w;
  const size_t b0 = (size_t)gw * 16;
  for (int rr=0; rr<16; ++rr){
    const float4* qrow = (const float4*)(Q0 + (b0 + rr)*NCN);
    float4 q4[4];
    float part = 0.f;
    #pragma unroll
    for (int j=0;j<4;++j){
      q4[j] = qrow[l + 64*j];
      float4 uu = ul4[l + 64*j];
      part += q4[j].x*uu.x; part += q4[j].y*uu.y;
      part += q4[j].z*uu.z; part += q4[j].w*uu.w;
    }
    #pragma unroll
    for (int off=32; off; off>>=1) part += __shfl_xor(part, off, 64);
    const float v = alpha / part;
    #pragma unroll
    for (int j=0;j<4;++j){
      float4 s = Sw4[l + 64*j];
      s.x += q4[j].x*v; s.y += q4[j].y*v; s.z += q4[j].z*v; s.w += q4[j].w*v;
      Sw4[l + 64*j] = s;
    }
  }
  __syncthreads();
  #pragma unroll
  for (int m=0;m<4;++m){
    int k = t + 256*m;
    S_part[(size_t)blockIdx.x*NCN + k] = ((Sw[0][k]+Sw[1][k])+(Sw[2][k]+Sw[3][k]));
  }
}

// ---------------- K4: u = r / colsum(S_part), parallel ----------------
__global__ __launch_bounds__(256) void k4_unew(
    const float* __restrict__ S_part, float* __restrict__ u)
{
  __shared__ float P[4][64];
  const int t = threadIdx.x;
  const int col = blockIdx.x*64 + (t & 63);
  const int s4 = t >> 6;
  float p = 0.f;
  for (int i=0;i<128;++i)
    p += S_part[(size_t)(s4*128 + i)*NCN + col];
  P[s4][t & 63] = p;
  __syncthreads();
  if (s4 == 0){
    float tot = ((P[0][t] + P[1][t]) + (P[2][t] + P[3][t]));
    u[col] = (1.0f/1024.0f) / tot;
  }
}

// ---------------- K5: final pass ----------------
__device__ __forceinline__ float comp4(const float4 v, int c){
  return (c==0)?v.x:(c==1)?v.y:(c==2)?v.z:v.w;
}

__global__ __launch_bounds__(256) void k5_final(
    const float* __restrict__ Q0, const float* __restrict__ u,
    float* __restrict__ softc_part, float* __restrict__ loss_part,
    int* __restrict__ hist_raw, int* __restrict__ hist_clu,
    float* __restrict__ out_ba)
{
  __shared__ __align__(16) float ul[NCN];
  __shared__ __align__(16) float Sw[4][NCN];
  __shared__ float lossw[4];
  const int t = threadIdx.x;
  const int w = t >> 6, l = t & 63;
  #pragma unroll
  for (int m=0;m<4;++m) ul[t + 256*m] = u[t + 256*m];
  #pragma unroll
  for (int m=0;m<16;++m) (&Sw[0][0])[t + 256*m] = 0.f;
  __syncthreads();

  const float4* ul4 = (const float4*)ul;
  float4* Sw4 = (float4*)&Sw[w][0];
  const int gw = blockIdx.x*4 + w;
  const size_t b0 = (size_t)gw * 32;
  float lacc = 0.f;
  for (int rr=0; rr<32; ++rr){
    const size_t b = b0 + rr;
    const float4* qrow = (const float4*)(Q0 + b*NCN);
    float4 q4[4], wv4[4];
    float part = 0.f;
    #pragma unroll
    for (int j=0;j<4;++j){
      q4[j] = qrow[l + 64*j];
      float4 uu = ul4[l + 64*j];
      wv4[j].x = uu.x*q4[j].x; wv4[j].y = uu.y*q4[j].y;
      wv4[j].z = uu.z*q4[j].z; wv4[j].w = uu.w*q4[j].w;
      part += wv4[j].x; part += wv4[j].y; part += wv4[j].z; part += wv4[j].w;
    }
    #pragma unroll
    for (int off=32; off; off>>=1) part += __shfl_xor(part, off, 64);
    const float inv = 1.0f / part;

    float smin = wv4[0].x * inv; int kmin = 4*l; float qat = q4[0].x;
    float qmax = q4[0].x;        int kmax = 4*l;
    #pragma unroll
    for (int j=0;j<4;++j){
      #pragma unroll
      for (int c=0;c<4;++c){
        if (j==0 && c==0) continue;
        float qv = comp4(q4[j], c);
        float sv = comp4(wv4[j], c) * inv;
        int k = 4*l + 256*j + c;
        if (sv < smin){ smin = sv; kmin = k; qat = qv; }
        if (qv > qmax){ qmax = qv; kmax = k; }
      }
    }
    #pragma unroll
    for (int off=32; off; off>>=1){
      float s2 = __shfl_xor(smin, off, 64);
      int   k2 = __shfl_xor(kmin, off, 64);
      float q2 = __shfl_xor(qat,  off, 64);
      if (s2 < smin || (s2 == smin && k2 < kmin)){ smin=s2; kmin=k2; qat=q2; }
      float m2 = __shfl_xor(qmax, off, 64);
      int   i2 = __shfl_xor(kmax, off, 64);
      if (m2 > qmax || (m2 == qmax && i2 < kmax)){ qmax=m2; kmax=i2; }
    }
    #pragma unroll
    for (int j=0;j<4;++j){
      float4 s = Sw4[l + 64*j];
      s.x += wv4[j].x*inv; s.y += wv4[j].y*inv;
      s.z += wv4[j].z*inv; s.w += wv4[j].w*inv;
      Sw4[l + 64*j] = s;
    }
    if (l == 0){
      out_ba[b] = (float)kmin;
      atomicAdd(&hist_clu[kmin], 1);
      atomicAdd(&hist_raw[kmax], 1);
      lacc += -0.5f * logf(qat);
    }
  }
  if (l == 0) lossw[w] = lacc;
  __syncthreads();
  #pragma unroll
  for (int m=0;m<4;++m){
    int k = t + 256*m;
    softc_part[(size_t)blockIdx.x*NCN + k] = ((Sw[0][k]+Sw[1][k])+(Sw[2][k]+Sw[3][k]));
  }
  if (t == 0) loss_part[blockIdx.x] = ((lossw[0]+lossw[1])+(lossw[2]+lossw[3]));
}

// ---------------- K6: deterministic combine + output write ----------------
__global__ __launch_bounds__(1024) void k6_fin(
    const float* __restrict__ softc_part, const float* __restrict__ loss_part,
    const int* __restrict__ hist_raw, const int* __restrict__ hist_clu,
    const int* __restrict__ raw_in, const int* __restrict__ clu_in,
    const float* __restrict__ tsoft_in, float* __restrict__ out)
{
  const int k = threadIdx.x;
  float s0=0.f,s1=0.f,s2=0.f,s3=0.f;
  for (int blk=0; blk<256; blk+=4){
    s0 += softc_part[(size_t)(blk+0)*NCN + k];
    s1 += softc_part[(size_t)(blk+1)*NCN + k];
    s2 += softc_part[(size_t)(blk+2)*NCN + k];
    s3 += softc_part[(size_t)(blk+3)*NCN + k];
  }
  const float s = ((s0+s1)+(s2+s3));
  out[1 + BN + k]           = s;
  out[1 + BN + NCN + k]     = (float)(raw_in[k] + hist_raw[k]);
  out[1 + BN + 2*NCN + k]   = (float)(clu_in[k] + hist_clu[k]);
  out[1 + BN + 3*NCN + k]   = tsoft_in[k] + s;
  if (k == 0){
    float ls = 0.f;
    for (int i=0;i<256;++i) ls += loss_part[i];
    out[0] = ls / 32768.0f;
  }
}

extern "C" void kernel_launch(void* const* d_in, const int* in_sizes, int n_in,
                              void* d_out, int out_size, void* d_ws, size_t ws_size,
                              hipStream_t stream) {
  (void)in_sizes; (void)n_in; (void)out_size; (void)ws_size;
  const float* x      = (const float*)d_in[0];
  const float* W1     = (const float*)d_in[1];
  const float* b1     = (const float*)d_in[2];
  const float* W2     = (const float*)d_in[3];
  const float* b2     = (const float*)d_in[4];
  const float* cent   = (const float*)d_in[5];
  const int*   clu_in = (const int*)d_in[6];
  const int*   raw_in = (const int*)d_in[7];
  const float* tsoft  = (const float*)d_in[8];
  float* out = (float*)d_out;

  // ws layout (float units). Lifetime aliasing:
  //  - X-splits (used only by k1) overlay the Q0 region (born in k2).
  //  - fv/cent-splits (born after k1) overlay the W-split region (dead after k1).
  float* ws        = (float*)d_ws;
  float* fv        = ws;                        // 4,194,304 floats
  float* Q0        = ws + 4194304;              // 33,554,432 (region sized 37,748,736)
  u16*   Xh        = (u16*)Q0;                  // 25,165,824 u16 each
  u16*   Xm        = Xh + 25165824;
  u16*   Xl        = Xm + 25165824;
  float* u         = ws + 41943040;             // 1024
  float* S_part    = u + 1024;                  // 524,288
  float* softc_par = S_part + 524288;           // 262,144
  float* loss_par  = softc_par + 262144;        // 256
  int*   hist_raw  = (int*)(loss_par + 256);    // 1024 ints
  int*   hist_clu  = hist_raw + 1024;           // 1024 ints
  float* wbase     = (float*)(hist_clu + 1024); // union region (6,488,064 floats)
  // k1 window: W splits
  u16* W1Th = (u16*)wbase;
  u16* W1Tm = W1Th + 1572864;
  u16* W1Tl = W1Tm + 1572864;
  u16* W2Th = W1Tl + 1572864;
  u16* W2Tm = W2Th + 262144;
  u16* W2Tl = W2Tm + 262144;
  // k2 window: fv + cent splits (alias over W splits)
  u16* fvh = (u16*)wbase;
  u16* fvm = fvh + 4194304;
  u16* fvl = fvm + 4194304;
  u16* ch  = fvl + 4194304;
  u16* cm  = ch  + 131072;
  u16* cl  = cm  + 131072;
  float* fvn = wbase + 6488064;                 // 32,768
  float* cn  = fvn + 32768;                     // 1,024

  // pre-splits
  c_split <<<24576, 256, 0, stream>>>(x, Xh, Xm, Xl, 6291456);       // X
  c_tsplit<<<dim3(12, 32), 256, 0, stream>>>(W1, 768, 2048, W1Th, W1Tm, W1Tl);
  c_tsplit<<<dim3(32, 2),  256, 0, stream>>>(W2, 2048, 128, W2Th, W2Tm, W2Tl);
  k0_init<<<1, 1024, 0, stream>>>(u, hist_raw, hist_clu);

  k1_mfma<<<512, 256, 0, stream>>>(Xh, Xm, Xl, W1Th, W1Tm, W1Tl, b1,
                                   W2Th, W2Tm, W2Tl, b2, fv);

  // k2 inputs (note: overwrites W-split region, k1 is done with it)
  c_split<<<4096, 256, 0, stream>>>(fv,   fvh, fvm, fvl, 1048576);
  c_split<<<128,  256, 0, stream>>>(cent, ch,  cm,  cl,  32768);
  c_norm <<<8192, 256, 0, stream>>>(fv,   fvn);
  c_norm <<<256,  256, 0, stream>>>(cent, cn);

  k2_mfma<<<512, 256, 0, stream>>>(fvh, fvm, fvl, ch, cm, cl, fvn, cn, Q0);

  for (int it = 0; it < 15; ++it){
    const float alpha = (it == 0) ? 1.0f : (1.0f/32768.0f);
    k3_pass<<<512, 256, 0, stream>>>(Q0, u, S_part, alpha);
    k4_unew<<<16, 256, 0, stream>>>(S_part, u);
  }
  k5_final<<<256, 256, 0, stream>>>(Q0, u, softc_par, loss_par,
                                    hist_raw, hist_clu, out + 1);
  k6_fin<<<1, 1024, 0, stream>>>(softc_par, loss_par, hist_raw, hist_clu,
                                 raw_in, clu_in, tsoft, out);
}